// Round 1
// baseline (677.909 us; speedup 1.0000x reference)
//
#include <hip/hip_runtime.h>
#include <math.h>

#define NN 64      // nodes per graph
#define HH 128     // hidden channels
#define NBB 8      // bessel basis
#define TT 32      // time embedding dim
#define BB 64      // batch
#define TS 8       // sender tile

__device__ __forceinline__ float silu_f(float x) { return x / (1.0f + __expf(-x)); }

// h[b,n,:] = emb[z[b,n],:] + gf[b,:] @ Wt ; v = 0
__global__ __launch_bounds__(128) void k_init(
    const float* __restrict__ emb, const int* __restrict__ z,
    const float* __restrict__ gf, const float* __restrict__ Wt,
    float* __restrict__ h, float* __restrict__ v) {
  int row = blockIdx.x;          // b*NN + n
  int b = row >> 6;
  int tid = threadIdx.x;
  int zi = z[row];
  float acc = emb[zi * HH + tid];
  const float* g = gf + b * TT;
#pragma unroll
  for (int k = 0; k < TT; ++k) acc += g[k] * Wt[k * HH + tid];
  h[row * HH + tid] = acc;
  v[(row * 3 + 0) * HH + tid] = 0.f;
  v[(row * 3 + 1) * HH + tid] = 0.f;
  v[(row * 3 + 2) * HH + tid] = 0.f;
}

// One block per (b, receiver r). Computes a0,a1 over all 63 senders, then
// fused update: hout = hin + (a0/63)@Wupd[l]; v += einsum(a1/63, Wmix[l]).
__global__ __launch_bounds__(128) void k_layer(
    const float* __restrict__ pos,
    const float* __restrict__ hin, float* __restrict__ hout,
    float* __restrict__ v,
    const float* __restrict__ Wr1, const float* __restrict__ Wr2,
    const float* __restrict__ Wupd, const float* __restrict__ Wmix, int l) {
  __shared__ float sh_pos[NN * 3];
  __shared__ float sh_S[TS][HH];
  __shared__ float sh_u[TS][4];
  __shared__ float sh_rb[TS][NBB];
  __shared__ float sh_a0[HH];
  __shared__ float sh_a1[3][HH];

  int blk = blockIdx.x;          // b*NN + r
  int b = blk >> 6, r = blk & 63;
  int tid = threadIdx.x;
  const float* posb = pos + b * NN * 3;
  for (int i = tid; i < NN * 3; i += 128) sh_pos[i] = posb[i];
  __syncthreads();

  float prx = sh_pos[r * 3 + 0], pry = sh_pos[r * 3 + 1], prz = sh_pos[r * 3 + 2];
  const float* Wr1l = Wr1 + l * NBB * HH;
  const float* Wr2l = Wr2 + l * HH * HH;

  float acc0 = 0.f, a1x = 0.f, a1y = 0.f, a1z = 0.f;

  for (int s0 = 0; s0 < NN; s0 += TS) {
    // --- per-sender prep (distance, unit vec, bessel basis w/ cutoff) ---
    if (tid < TS) {
      int s = s0 + tid;
      float dx = prx - sh_pos[s * 3 + 0];   // ev = pos[rcv] - pos[snd]
      float dy = pry - sh_pos[s * 3 + 1];
      float dz = prz - sh_pos[s * 3 + 2];
      float rr = sqrtf(dx * dx + dy * dy + dz * dz + 1e-12f);
      float inv = 1.0f / rr;
      sh_u[tid][0] = dx * inv; sh_u[tid][1] = dy * inv; sh_u[tid][2] = dz * inv;
      const float PI_OVER_5 = 0.628318530717958647692f;
      float fc = (s != r && rr < 5.0f) ? 0.5f * (cosf(PI_OVER_5 * rr) + 1.0f) : 0.0f;
      float base = PI_OVER_5 * rr;
      float sc = inv * fc;
#pragma unroll
      for (int k = 0; k < NBB; ++k)
        sh_rb[tid][k] = sinf((float)(k + 1) * base) * sc;
    }
    __syncthreads();

    // --- S[j][g] = silu(rb @ Wr1[l]) for the 8 senders of this tile ---
#pragma unroll
    for (int j = 0; j < TS; ++j) {
      float a = 0.f;
#pragma unroll
      for (int k = 0; k < NBB; ++k) a += sh_rb[j][k] * Wr1l[k * HH + tid];
      sh_S[j][tid] = silu_f(a);
    }
    __syncthreads();

    // --- w[j][tid] = S[j][:] @ Wr2[l][:, tid], register-tiled over j ---
    float wacc[TS];
#pragma unroll
    for (int j = 0; j < TS; ++j) wacc[j] = 0.f;
    for (int g = 0; g < HH; g += 4) {
      float w0 = Wr2l[(g + 0) * HH + tid];
      float w1 = Wr2l[(g + 1) * HH + tid];
      float w2 = Wr2l[(g + 2) * HH + tid];
      float w3 = Wr2l[(g + 3) * HH + tid];
#pragma unroll
      for (int j = 0; j < TS; ++j) {
        float4 sv = *(const float4*)&sh_S[j][g];
        wacc[j] += sv.x * w0 + sv.y * w1 + sv.z * w2 + sv.w * w3;
      }
    }

    // --- messages + accumulate (s==r has rb=0 -> S=0 -> w=0, contributes 0) ---
#pragma unroll
    for (int j = 0; j < TS; ++j) {
      int s = s0 + j;
      float m0 = wacc[j] * hin[(b * NN + s) * HH + tid];
      acc0 += m0;
      a1x += m0 * sh_u[j][0];
      a1y += m0 * sh_u[j][1];
      a1z += m0 * sh_u[j][2];
    }
    __syncthreads();
  }

  // --- fused node update (block owns row r; no races) ---
  const float invAvg = 1.0f / 63.0f;
  sh_a0[tid] = acc0 * invAvg;
  sh_a1[0][tid] = a1x * invAvg;
  sh_a1[1][tid] = a1y * invAvg;
  sh_a1[2][tid] = a1z * invAvg;
  __syncthreads();

  const float* Wul = Wupd + l * HH * HH;
  const float* Wml = Wmix + l * HH * HH;
  float hacc = hin[blk * HH + tid];
  float vx = v[(blk * 3 + 0) * HH + tid];
  float vy = v[(blk * 3 + 1) * HH + tid];
  float vz = v[(blk * 3 + 2) * HH + tid];
  for (int g = 0; g < HH; ++g) {
    hacc += sh_a0[g] * Wul[g * HH + tid];
    float wm = Wml[g * HH + tid];
    vx += sh_a1[0][g] * wm;
    vy += sh_a1[1][g] * wm;
    vz += sh_a1[2][g] * wm;
  }
  hout[blk * HH + tid] = hacc;
  v[(blk * 3 + 0) * HH + tid] = vx;
  v[(blk * 3 + 1) * HH + tid] = vy;
  v[(blk * 3 + 2) * HH + tid] = vz;
}

// g = silu(h@Wg1)@Wg2 ; out[n,d] = sum_h v[n,h,d]*g[n,h] * final_scaling
__global__ __launch_bounds__(128) void k_readout(
    const float* __restrict__ h, const float* __restrict__ v,
    const float* __restrict__ Wg1, const float* __restrict__ Wg2,
    const float* __restrict__ fs, float* __restrict__ out) {
  __shared__ float sh_h[HH];
  __shared__ float sh_q[HH];
  __shared__ float red[2][3];
  int row = blockIdx.x;
  int tid = threadIdx.x;
  sh_h[tid] = h[row * HH + tid];
  __syncthreads();
  float a = 0.f;
  for (int k = 0; k < HH; ++k) a += sh_h[k] * Wg1[k * HH + tid];
  sh_q[tid] = silu_f(a);
  __syncthreads();
  float g = 0.f;
  for (int k = 0; k < HH; ++k) g += sh_q[k] * Wg2[k * HH + tid];
  float px = v[(row * 3 + 0) * HH + tid] * g;
  float py = v[(row * 3 + 1) * HH + tid] * g;
  float pz = v[(row * 3 + 2) * HH + tid] * g;
#pragma unroll
  for (int off = 32; off > 0; off >>= 1) {
    px += __shfl_down(px, off);
    py += __shfl_down(py, off);
    pz += __shfl_down(pz, off);
  }
  int wid = tid >> 6, lane = tid & 63;
  if (lane == 0) { red[wid][0] = px; red[wid][1] = py; red[wid][2] = pz; }
  __syncthreads();
  if (tid < 3) out[row * 3 + tid] = (red[0][tid] + red[1][tid]) * fs[0];
}

extern "C" void kernel_launch(void* const* d_in, const int* in_sizes, int n_in,
                              void* d_out, int out_size, void* d_ws, size_t ws_size,
                              hipStream_t stream) {
  const float* pos  = (const float*)d_in[0];
  const int*   z    = (const int*)d_in[1];
  const float* gf   = (const float*)d_in[2];
  const float* emb  = (const float*)d_in[3];
  const float* Wt   = (const float*)d_in[4];
  const float* Wr1  = (const float*)d_in[5];
  const float* Wr2  = (const float*)d_in[6];
  const float* Wupd = (const float*)d_in[7];
  const float* Wmix = (const float*)d_in[8];
  const float* Wg1  = (const float*)d_in[9];
  const float* Wg2  = (const float*)d_in[10];
  const float* fs   = (const float*)d_in[11];
  float* out = (float*)d_out;

  float* ws = (float*)d_ws;
  const size_t HN = (size_t)BB * NN * HH;   // 524288
  float* hA = ws;
  float* hB = ws + HN;
  float* v  = ws + 2 * HN;                  // 3*HN floats

  dim3 grid(BB * NN), blk(128);
  k_init<<<grid, blk, 0, stream>>>(emb, z, gf, Wt, hA, v);
  k_layer<<<grid, blk, 0, stream>>>(pos, hA, hB, v, Wr1, Wr2, Wupd, Wmix, 0);
  k_layer<<<grid, blk, 0, stream>>>(pos, hB, hA, v, Wr1, Wr2, Wupd, Wmix, 1);
  k_readout<<<grid, blk, 0, stream>>>(hA, v, Wg1, Wg2, fs, out);
}

// Round 2
// 224.767 us; speedup vs baseline: 3.0161x; 3.0161x over previous
//
#include <hip/hip_runtime.h>
#include <math.h>

#define NN 64      // nodes per graph
#define HH 128     // hidden channels
#define NBB 8      // bessel basis
#define TT 32      // time embedding dim
#define BB 64      // batch

typedef __attribute__((ext_vector_type(8))) short short8;
typedef __attribute__((ext_vector_type(4))) float f32x4;

__device__ __forceinline__ float silu_f(float x) { return x / (1.0f + __expf(-x)); }

__device__ __forceinline__ unsigned short f2bf(float x) {
  union { float f; unsigned u; } v; v.f = x;
  unsigned r = v.u + 0x7FFFu + ((v.u >> 16) & 1u);   // round-to-nearest-even
  return (unsigned short)(r >> 16);
}

// Pack Wr2 (fp32 [L][128][128]) -> bf16 in MFMA B-fragment order:
// dst[(((l*4+kt)*128 + n)*4 + q)*8 + j] = Wr2[l][k][n], k = kt*32 + q*8 + j
__global__ __launch_bounds__(256) void k_prep(const float* __restrict__ Wr2,
                                              unsigned short* __restrict__ Wr2p) {
  int idx = blockIdx.x * 256 + threadIdx.x;       // 0..32767
  int l = idx >> 14;
  int k = (idx >> 7) & 127;
  int n = idx & 127;
  int kt = k >> 5, q = (k >> 3) & 3, j = k & 7;
  int dst = ((((l * 4 + kt) * 128 + n) * 4 + q) * 8) + j;
  Wr2p[dst] = f2bf(Wr2[idx]);
}

// h[b,n,:] = emb[z[b,n],:] + gf[b,:] @ Wt ; v = 0
__global__ __launch_bounds__(128) void k_init(
    const float* __restrict__ emb, const int* __restrict__ z,
    const float* __restrict__ gf, const float* __restrict__ Wt,
    float* __restrict__ h, float* __restrict__ v) {
  int row = blockIdx.x;          // b*NN + n
  int b = row >> 6;
  int tid = threadIdx.x;
  int zi = z[row];
  float acc = emb[zi * HH + tid];
  const float* g = gf + b * TT;
#pragma unroll
  for (int k = 0; k < TT; ++k) acc += g[k] * Wt[k * HH + tid];
  h[row * HH + tid] = acc;
  v[(row * 3 + 0) * HH + tid] = 0.f;
  v[(row * 3 + 1) * HH + tid] = 0.f;
  v[(row * 3 + 2) * HH + tid] = 0.f;
}

// One block (128 thr = 2 waves) per (b, receiver r).
// Stage A: rb/u.  Stage B: S = silu(rb@Wr1) -> bf16 LDS.
// GEMM: w = S @ Wr2 via mfma 16x16x32 bf16 (wave w owns columns w*64..w*64+63).
// Epilogue: a0/a1 from C-regs * h * u, quad-reduce, then fused
// hout = hin + (a0/63)@Wupd; v += (a1/63)@Wmix.
__global__ __launch_bounds__(128) void k_layer(
    const float* __restrict__ pos,
    const float* __restrict__ hin, float* __restrict__ hout,
    float* __restrict__ v,
    const float* __restrict__ Wr1, const unsigned short* __restrict__ Wr2p,
    const float* __restrict__ Wupd, const float* __restrict__ Wmix, int l) {
  __shared__ __align__(16) float sh_pos[NN * 3];
  __shared__ __align__(16) unsigned short sh_S[NN][136];   // +8 bf16 pad: conflict-free frags
  __shared__ __align__(16) float sh_rb[NN][8];
  __shared__ __align__(16) float sh_u[NN][4];
  __shared__ __align__(16) float sh_acc[HH][4];            // [g][a0,a1x,a1y,a1z]

  int blk = blockIdx.x;          // b*NN + r
  int b = blk >> 6, r = blk & 63;
  int tid = threadIdx.x;
  int w = tid >> 6, lane = tid & 63;

  for (int i = tid; i < NN * 3; i += 128) sh_pos[i] = pos[b * NN * 3 + i];
  __syncthreads();

  float prx = sh_pos[r * 3 + 0], pry = sh_pos[r * 3 + 1], prz = sh_pos[r * 3 + 2];

  // ---- Stage A: per-sender geometry + bessel basis (wave w covers s in [w*32, w*32+32)) ----
  if (lane < 32) {
    int s = w * 32 + lane;
    float dx = prx - sh_pos[s * 3 + 0];
    float dy = pry - sh_pos[s * 3 + 1];
    float dz = prz - sh_pos[s * 3 + 2];
    float rr = sqrtf(dx * dx + dy * dy + dz * dz + 1e-12f);
    float inv = 1.0f / rr;
    sh_u[s][0] = dx * inv; sh_u[s][1] = dy * inv; sh_u[s][2] = dz * inv; sh_u[s][3] = 0.f;
    const float PI_OVER_5 = 0.628318530717958647692f;
    float fc = (s != r && rr < 5.0f) ? 0.5f * (__cosf(PI_OVER_5 * rr) + 1.0f) : 0.0f;
    float base = PI_OVER_5 * rr;
    float sc = inv * fc;
#pragma unroll
    for (int k = 0; k < NBB; ++k)
      sh_rb[s][k] = __sinf((float)(k + 1) * base) * sc;
  }
  __syncthreads();

  // ---- Stage B: S[s][c] = silu(rb[s] @ Wr1[:,c]) -> bf16, rows of wave's s-range ----
  {
    const float* Wr1l = Wr1 + l * NBB * HH;
    int c0 = 2 * lane;
    float wc0[NBB], wc1[NBB];
#pragma unroll
    for (int k = 0; k < NBB; ++k) { wc0[k] = Wr1l[k * HH + c0]; wc1[k] = Wr1l[k * HH + c0 + 1]; }
    int sbase = w * 32;
    for (int si = 0; si < 32; ++si) {
      int s = sbase + si;
      f32x4 r0 = *(const f32x4*)&sh_rb[s][0];
      f32x4 r1 = *(const f32x4*)&sh_rb[s][4];
      float a0 = r0.x*wc0[0] + r0.y*wc0[1] + r0.z*wc0[2] + r0.w*wc0[3]
               + r1.x*wc0[4] + r1.y*wc0[5] + r1.z*wc0[6] + r1.w*wc0[7];
      float a1 = r0.x*wc1[0] + r0.y*wc1[1] + r0.z*wc1[2] + r0.w*wc1[3]
               + r1.x*wc1[4] + r1.y*wc1[5] + r1.z*wc1[6] + r1.w*wc1[7];
      unsigned packed = (unsigned)f2bf(silu_f(a0)) | ((unsigned)f2bf(silu_f(a1)) << 16);
      *(unsigned*)&sh_S[s][c0] = packed;
    }
  }
  __syncthreads();

  // ---- GEMM + message epilogue ----
  const unsigned short* Bbase = Wr2p + l * 16384;
  int nlo = lane & 15, quad = lane >> 4;
  float acc0[4] = {0.f, 0.f, 0.f, 0.f};
  float a1x[4] = {0.f, 0.f, 0.f, 0.f};
  float a1y[4] = {0.f, 0.f, 0.f, 0.f};
  float a1z[4] = {0.f, 0.f, 0.f, 0.f};
  const float* hb = hin + (size_t)b * NN * HH;

#pragma unroll
  for (int mt = 0; mt < 4; ++mt) {
    // A-frags for this M-tile: A[m=nlo][k=kt*32+quad*8+j], s = mt*16+nlo
    short8 afr[4];
    int s_a = mt * 16 + nlo;
#pragma unroll
    for (int kt = 0; kt < 4; ++kt)
      afr[kt] = *(const short8*)&sh_S[s_a][kt * 32 + quad * 8];
    // u for this lane's epilogue rows: s = mt*16 + quad*4 + reg
    float ux[4], uy[4], uz[4];
#pragma unroll
    for (int reg = 0; reg < 4; ++reg) {
      int s = mt * 16 + quad * 4 + reg;
      ux[reg] = sh_u[s][0]; uy[reg] = sh_u[s][1]; uz[reg] = sh_u[s][2];
    }
#pragma unroll
    for (int nt = 0; nt < 4; ++nt) {
      int c = w * 64 + nt * 16 + nlo;
      f32x4 C = {0.f, 0.f, 0.f, 0.f};
#pragma unroll
      for (int kt = 0; kt < 4; ++kt) {
        short8 bfr = *(const short8*)&Bbase[((kt * 128 + c) * 4 + quad) * 8];
        C = __builtin_amdgcn_mfma_f32_16x16x32_bf16(afr[kt], bfr, C, 0, 0, 0);
      }
#pragma unroll
      for (int reg = 0; reg < 4; ++reg) {
        int s = mt * 16 + quad * 4 + reg;
        float m0 = C[reg] * hb[s * HH + c];
        acc0[nt] += m0;
        a1x[nt] += m0 * ux[reg];
        a1y[nt] += m0 * uy[reg];
        a1z[nt] += m0 * uz[reg];
      }
    }
  }

  // quad-reduce (lanes differing in bits 4/5 hold same column c) and stash to LDS
  const float invAvg = 1.0f / 63.0f;
#pragma unroll
  for (int nt = 0; nt < 4; ++nt) {
    float q0 = acc0[nt], q1 = a1x[nt], q2 = a1y[nt], q3 = a1z[nt];
    q0 += __shfl_xor(q0, 16); q0 += __shfl_xor(q0, 32);
    q1 += __shfl_xor(q1, 16); q1 += __shfl_xor(q1, 32);
    q2 += __shfl_xor(q2, 16); q2 += __shfl_xor(q2, 32);
    q3 += __shfl_xor(q3, 16); q3 += __shfl_xor(q3, 32);
    if (quad == 0) {
      int c = w * 64 + nt * 16 + nlo;
      sh_acc[c][0] = q0 * invAvg;
      sh_acc[c][1] = q1 * invAvg;
      sh_acc[c][2] = q2 * invAvg;
      sh_acc[c][3] = q3 * invAvg;
    }
  }
  __syncthreads();

  // ---- fused node update: hout = hin + a0@Wupd ; v += a1@Wmix ----
  {
    int c = tid;
    const float* Wul = Wupd + l * HH * HH;
    const float* Wml = Wmix + l * HH * HH;
    float hacc = hin[(size_t)blk * HH + c];
    float vx = v[((size_t)blk * 3 + 0) * HH + c];
    float vy = v[((size_t)blk * 3 + 1) * HH + c];
    float vz = v[((size_t)blk * 3 + 2) * HH + c];
    for (int g = 0; g < HH; ++g) {
      f32x4 a = *(const f32x4*)&sh_acc[g][0];   // broadcast
      float wu = Wul[g * HH + c];
      float wm = Wml[g * HH + c];
      hacc += a.x * wu;
      vx += a.y * wm;
      vy += a.z * wm;
      vz += a.w * wm;
    }
    hout[(size_t)blk * HH + c] = hacc;
    v[((size_t)blk * 3 + 0) * HH + c] = vx;
    v[((size_t)blk * 3 + 1) * HH + c] = vy;
    v[((size_t)blk * 3 + 2) * HH + c] = vz;
  }
}

// g = silu(h@Wg1)@Wg2 ; out[n,d] = sum_h v[n,h,d]*g[n,h] * final_scaling
__global__ __launch_bounds__(128) void k_readout(
    const float* __restrict__ h, const float* __restrict__ v,
    const float* __restrict__ Wg1, const float* __restrict__ Wg2,
    const float* __restrict__ fs, float* __restrict__ out) {
  __shared__ float sh_h[HH];
  __shared__ float sh_q[HH];
  __shared__ float red[2][3];
  int row = blockIdx.x;
  int tid = threadIdx.x;
  sh_h[tid] = h[row * HH + tid];
  __syncthreads();
  float a = 0.f;
  for (int k = 0; k < HH; ++k) a += sh_h[k] * Wg1[k * HH + tid];
  sh_q[tid] = silu_f(a);
  __syncthreads();
  float g = 0.f;
  for (int k = 0; k < HH; ++k) g += sh_q[k] * Wg2[k * HH + tid];
  float px = v[(row * 3 + 0) * HH + tid] * g;
  float py = v[(row * 3 + 1) * HH + tid] * g;
  float pz = v[(row * 3 + 2) * HH + tid] * g;
#pragma unroll
  for (int off = 32; off > 0; off >>= 1) {
    px += __shfl_down(px, off);
    py += __shfl_down(py, off);
    pz += __shfl_down(pz, off);
  }
  int wid = tid >> 6, lane = tid & 63;
  if (lane == 0) { red[wid][0] = px; red[wid][1] = py; red[wid][2] = pz; }
  __syncthreads();
  if (tid < 3) out[row * 3 + tid] = (red[0][tid] + red[1][tid]) * fs[0];
}

extern "C" void kernel_launch(void* const* d_in, const int* in_sizes, int n_in,
                              void* d_out, int out_size, void* d_ws, size_t ws_size,
                              hipStream_t stream) {
  const float* pos  = (const float*)d_in[0];
  const int*   z    = (const int*)d_in[1];
  const float* gf   = (const float*)d_in[2];
  const float* emb  = (const float*)d_in[3];
  const float* Wt   = (const float*)d_in[4];
  const float* Wr1  = (const float*)d_in[5];
  const float* Wr2  = (const float*)d_in[6];
  const float* Wupd = (const float*)d_in[7];
  const float* Wmix = (const float*)d_in[8];
  const float* Wg1  = (const float*)d_in[9];
  const float* Wg2  = (const float*)d_in[10];
  const float* fs   = (const float*)d_in[11];
  float* out = (float*)d_out;

  float* ws = (float*)d_ws;
  const size_t HN = (size_t)BB * NN * HH;   // 524288
  float* hA = ws;
  float* hB = ws + HN;
  float* v  = ws + 2 * HN;                  // 3*HN floats
  unsigned short* Wr2p = (unsigned short*)(ws + 5 * HN);  // 32768 bf16

  dim3 grid(BB * NN), blk(128);
  k_prep<<<dim3(128), dim3(256), 0, stream>>>(Wr2, Wr2p);
  k_init<<<grid, blk, 0, stream>>>(emb, z, gf, Wt, hA, v);
  k_layer<<<grid, blk, 0, stream>>>(pos, hA, hB, v, Wr1, Wr2p, Wupd, Wmix, 0);
  k_layer<<<grid, blk, 0, stream>>>(pos, hB, hA, v, Wr1, Wr2p, Wupd, Wmix, 1);
  k_readout<<<grid, blk, 0, stream>>>(hA, v, Wg1, Wg2, fs, out);
}

// Round 3
// 214.814 us; speedup vs baseline: 3.1558x; 1.0463x over previous
//
#include <hip/hip_runtime.h>
#include <math.h>

#define NN 64      // nodes per graph
#define HH 128     // hidden channels
#define NBB 8      // bessel basis
#define TT 32      // time embedding dim
#define BB 64      // batch

typedef __attribute__((ext_vector_type(8))) short short8;
typedef __attribute__((ext_vector_type(4))) float f32x4;
typedef __attribute__((ext_vector_type(2))) float f32x2;

__device__ __forceinline__ float silu_f(float x) {
  return x * __builtin_amdgcn_rcpf(1.0f + __expf(-x));
}

__device__ __forceinline__ unsigned short f2bf(float x) {
  union { float f; unsigned u; } v; v.f = x;
  unsigned r = v.u + 0x7FFFu + ((v.u >> 16) & 1u);   // round-to-nearest-even
  return (unsigned short)(r >> 16);
}

// Pack Wr2 (fp32 [L][128][128]) -> bf16 in MFMA B-fragment order:
// dst[(((l*4+kt)*128 + n)*4 + q)*8 + j] = Wr2[l][k][n], k = kt*32 + q*8 + j
__global__ __launch_bounds__(256) void k_prep(const float* __restrict__ Wr2,
                                              unsigned short* __restrict__ Wr2p) {
  int idx = blockIdx.x * 256 + threadIdx.x;       // 0..32767
  int l = idx >> 14;
  int k = (idx >> 7) & 127;
  int n = idx & 127;
  int kt = k >> 5, q = (k >> 3) & 3, j = k & 7;
  int dst = ((((l * 4 + kt) * 128 + n) * 4 + q) * 8) + j;
  Wr2p[dst] = f2bf(Wr2[idx]);
}

// h[b,n,:] = emb[z[b,n],:] + gf[b,:] @ Wt ; v = 0
__global__ __launch_bounds__(128) void k_init(
    const float* __restrict__ emb, const int* __restrict__ z,
    const float* __restrict__ gf, const float* __restrict__ Wt,
    float* __restrict__ h, float* __restrict__ v) {
  int row = blockIdx.x;          // b*NN + n
  int b = row >> 6;
  int tid = threadIdx.x;
  int zi = z[row];
  float acc = emb[zi * HH + tid];
  const float* g = gf + b * TT;
#pragma unroll
  for (int k = 0; k < TT; ++k) acc += g[k] * Wt[k * HH + tid];
  h[row * HH + tid] = acc;
  v[(row * 3 + 0) * HH + tid] = 0.f;
  v[(row * 3 + 1) * HH + tid] = 0.f;
  v[(row * 3 + 2) * HH + tid] = 0.f;
}

// One block (256 thr = 4 waves) per (b, receiver r).
// A: rb/u (wave0). B: S = silu(rb@Wr1) -> bf16 LDS (16 senders/wave).
// GEMM: w = S@Wr2 via mfma 16x16x32 bf16; wave w owns columns w*32..w*32+31.
// Epilogue: a0/a1 from C-regs * h * u, quad-reduce -> sh_acc.
// Update (all 256 thr, c-vectorized, 4-way g-split, LDS combine):
//   hout = hin + (a0/63)@Wupd ; v += (a1/63)@Wmix.
__global__ __launch_bounds__(256) void k_layer(
    const float* __restrict__ pos,
    const float* __restrict__ hin, float* __restrict__ hout,
    float* __restrict__ v,
    const float* __restrict__ Wr1, const unsigned short* __restrict__ Wr2p,
    const float* __restrict__ Wupd, const float* __restrict__ Wmix, int l) {
  __shared__ __align__(16) float sh_pos[NN * 3];
  __shared__ __align__(16) unsigned short sh_S[NN][136];   // +8 pad; aliased as sh_red later
  __shared__ __align__(16) float sh_rb[NN][8];
  __shared__ __align__(16) float sh_u[NN][4];
  __shared__ __align__(16) float sh_acc[HH][4];            // [g][a0,a1x,a1y,a1z]

  int blk = blockIdx.x;          // b*NN + r
  int b = blk >> 6, r = blk & 63;
  int tid = threadIdx.x;
  int w = tid >> 6, lane = tid & 63;

  if (tid < NN * 3) sh_pos[tid] = pos[b * NN * 3 + tid];
  __syncthreads();

  // ---- Stage A: per-sender geometry + bessel basis (wave 0, s = lane) ----
  if (tid < NN) {
    int s = tid;
    float dx = sh_pos[r * 3 + 0] - sh_pos[s * 3 + 0];
    float dy = sh_pos[r * 3 + 1] - sh_pos[s * 3 + 1];
    float dz = sh_pos[r * 3 + 2] - sh_pos[s * 3 + 2];
    float rr = sqrtf(dx * dx + dy * dy + dz * dz + 1e-12f);
    float inv = __builtin_amdgcn_rcpf(rr);
    sh_u[s][0] = dx * inv; sh_u[s][1] = dy * inv; sh_u[s][2] = dz * inv; sh_u[s][3] = 0.f;
    const float PI_OVER_5 = 0.628318530717958647692f;
    float fc = (s != r && rr < 5.0f) ? 0.5f * (__cosf(PI_OVER_5 * rr) + 1.0f) : 0.0f;
    float base = PI_OVER_5 * rr;
    float sc = inv * fc;
#pragma unroll
    for (int k = 0; k < NBB; ++k)
      sh_rb[s][k] = __sinf((float)(k + 1) * base) * sc;
  }
  __syncthreads();

  // ---- Stage B: S[s][c] = silu(rb[s]@Wr1[:,c]) -> bf16; wave w: s in [w*16, w*16+16) ----
  {
    const float* Wr1l = Wr1 + l * NBB * HH;
    int c0 = 2 * lane;
    float wc0[NBB], wc1[NBB];
#pragma unroll
    for (int k = 0; k < NBB; ++k) { wc0[k] = Wr1l[k * HH + c0]; wc1[k] = Wr1l[k * HH + c0 + 1]; }
    int sbase = w * 16;
#pragma unroll 4
    for (int si = 0; si < 16; ++si) {
      int s = sbase + si;
      f32x4 r0 = *(const f32x4*)&sh_rb[s][0];
      f32x4 r1 = *(const f32x4*)&sh_rb[s][4];
      float a0 = r0.x*wc0[0] + r0.y*wc0[1] + r0.z*wc0[2] + r0.w*wc0[3]
               + r1.x*wc0[4] + r1.y*wc0[5] + r1.z*wc0[6] + r1.w*wc0[7];
      float a1 = r0.x*wc1[0] + r0.y*wc1[1] + r0.z*wc1[2] + r0.w*wc1[3]
               + r1.x*wc1[4] + r1.y*wc1[5] + r1.z*wc1[6] + r1.w*wc1[7];
      unsigned packed = (unsigned)f2bf(silu_f(a0)) | ((unsigned)f2bf(silu_f(a1)) << 16);
      *(unsigned*)&sh_S[s][c0] = packed;
    }
  }
  __syncthreads();

  // ---- GEMM + message epilogue (wave w owns c in [w*32, w*32+32)) ----
  {
    const unsigned short* Bbase = Wr2p + l * 16384;
    int nlo = lane & 15, quad = lane >> 4;
    // hoist the wave's 8 B-frags
    short8 bfr[4][2];
#pragma unroll
    for (int kt = 0; kt < 4; ++kt)
#pragma unroll
      for (int nt = 0; nt < 2; ++nt) {
        int c = w * 32 + nt * 16 + nlo;
        bfr[kt][nt] = *(const short8*)&Bbase[((kt * 128 + c) * 4 + quad) * 8];
      }
    float acc0[2] = {0.f, 0.f};
    float a1x[2] = {0.f, 0.f};
    float a1y[2] = {0.f, 0.f};
    float a1z[2] = {0.f, 0.f};
    const float* hb = hin + (size_t)b * NN * HH;

#pragma unroll
    for (int mt = 0; mt < 4; ++mt) {
      short8 afr[4];
      int s_a = mt * 16 + nlo;
#pragma unroll
      for (int kt = 0; kt < 4; ++kt)
        afr[kt] = *(const short8*)&sh_S[s_a][kt * 32 + quad * 8];
      float ux[4], uy[4], uz[4];
#pragma unroll
      for (int reg = 0; reg < 4; ++reg) {
        int s = mt * 16 + quad * 4 + reg;
        ux[reg] = sh_u[s][0]; uy[reg] = sh_u[s][1]; uz[reg] = sh_u[s][2];
      }
#pragma unroll
      for (int nt = 0; nt < 2; ++nt) {
        int c = w * 32 + nt * 16 + nlo;
        f32x4 C = {0.f, 0.f, 0.f, 0.f};
#pragma unroll
        for (int kt = 0; kt < 4; ++kt)
          C = __builtin_amdgcn_mfma_f32_16x16x32_bf16(afr[kt], bfr[kt][nt], C, 0, 0, 0);
#pragma unroll
        for (int reg = 0; reg < 4; ++reg) {
          int s = mt * 16 + quad * 4 + reg;
          float m0 = C[reg] * hb[s * HH + c];
          acc0[nt] += m0;
          a1x[nt] += m0 * ux[reg];
          a1y[nt] += m0 * uy[reg];
          a1z[nt] += m0 * uz[reg];
        }
      }
    }

    // quad-reduce (lanes differing in bits 4/5 hold same column c) -> sh_acc
    const float invAvg = 1.0f / 63.0f;
#pragma unroll
    for (int nt = 0; nt < 2; ++nt) {
      float q0 = acc0[nt], q1 = a1x[nt], q2 = a1y[nt], q3 = a1z[nt];
      q0 += __shfl_xor(q0, 16); q0 += __shfl_xor(q0, 32);
      q1 += __shfl_xor(q1, 16); q1 += __shfl_xor(q1, 32);
      q2 += __shfl_xor(q2, 16); q2 += __shfl_xor(q2, 32);
      q3 += __shfl_xor(q3, 16); q3 += __shfl_xor(q3, 32);
      if (quad == 0) {
        int c = w * 32 + nt * 16 + nlo;
        sh_acc[c][0] = q0 * invAvg;
        sh_acc[c][1] = q1 * invAvg;
        sh_acc[c][2] = q2 * invAvg;
        sh_acc[c][3] = q3 * invAvg;
      }
    }
  }
  __syncthreads();   // sh_acc ready; also: all sh_S reads done -> safe to alias

  // ---- fused node update, c-vectorized + 4-way g-split ----
  float* sh_red = (float*)&sh_S[0][0];   // [4 val][4 gq][128 c] = 8 KB, aliases dead sh_S
  {
    int c2 = (tid & 63) * 2;
    int gq = tid >> 6;                    // == wave id; uniform per wave
    const float* Wul = Wupd + l * HH * HH;
    const float* Wml = Wmix + l * HH * HH;
    float h0 = 0.f, h1 = 0.f, x0 = 0.f, x1 = 0.f, y0 = 0.f, y1 = 0.f, z0 = 0.f, z1 = 0.f;
    int gend = gq * 32 + 32;
#pragma unroll 4
    for (int g = gq * 32; g < gend; ++g) {
      f32x4 a = *(const f32x4*)&sh_acc[g][0];             // wave-broadcast
      f32x2 wu = *(const f32x2*)&Wul[g * HH + c2];
      f32x2 wm = *(const f32x2*)&Wml[g * HH + c2];
      h0 += a.x * wu.x; h1 += a.x * wu.y;
      x0 += a.y * wm.x; x1 += a.y * wm.y;
      y0 += a.z * wm.x; y1 += a.z * wm.y;
      z0 += a.w * wm.x; z1 += a.w * wm.y;
    }
    sh_red[0 * 512 + gq * 128 + c2] = h0; sh_red[0 * 512 + gq * 128 + c2 + 1] = h1;
    sh_red[1 * 512 + gq * 128 + c2] = x0; sh_red[1 * 512 + gq * 128 + c2 + 1] = x1;
    sh_red[2 * 512 + gq * 128 + c2] = y0; sh_red[2 * 512 + gq * 128 + c2 + 1] = y1;
    sh_red[3 * 512 + gq * 128 + c2] = z0; sh_red[3 * 512 + gq * 128 + c2 + 1] = z1;
  }
  __syncthreads();

  if (tid < HH) {
    int c = tid;
    float hs = sh_red[c] + sh_red[128 + c] + sh_red[256 + c] + sh_red[384 + c];
    float xs = sh_red[512 + c] + sh_red[512 + 128 + c] + sh_red[512 + 256 + c] + sh_red[512 + 384 + c];
    float ys = sh_red[1024 + c] + sh_red[1024 + 128 + c] + sh_red[1024 + 256 + c] + sh_red[1024 + 384 + c];
    float zs = sh_red[1536 + c] + sh_red[1536 + 128 + c] + sh_red[1536 + 256 + c] + sh_red[1536 + 384 + c];
    hout[(size_t)blk * HH + c] = hin[(size_t)blk * HH + c] + hs;
    v[((size_t)blk * 3 + 0) * HH + c] += xs;
    v[((size_t)blk * 3 + 1) * HH + c] += ys;
    v[((size_t)blk * 3 + 2) * HH + c] += zs;
  }
}

// g = silu(h@Wg1)@Wg2 ; out[n,d] = sum_h v[n,h,d]*g[n,h] * final_scaling
__global__ __launch_bounds__(128) void k_readout(
    const float* __restrict__ h, const float* __restrict__ v,
    const float* __restrict__ Wg1, const float* __restrict__ Wg2,
    const float* __restrict__ fs, float* __restrict__ out) {
  __shared__ float sh_h[HH];
  __shared__ float sh_q[HH];
  __shared__ float red[2][3];
  int row = blockIdx.x;
  int tid = threadIdx.x;
  sh_h[tid] = h[row * HH + tid];
  __syncthreads();
  float a = 0.f;
  for (int k = 0; k < HH; ++k) a += sh_h[k] * Wg1[k * HH + tid];
  sh_q[tid] = silu_f(a);
  __syncthreads();
  float g = 0.f;
  for (int k = 0; k < HH; ++k) g += sh_q[k] * Wg2[k * HH + tid];
  float px = v[(row * 3 + 0) * HH + tid] * g;
  float py = v[(row * 3 + 1) * HH + tid] * g;
  float pz = v[(row * 3 + 2) * HH + tid] * g;
#pragma unroll
  for (int off = 32; off > 0; off >>= 1) {
    px += __shfl_down(px, off);
    py += __shfl_down(py, off);
    pz += __shfl_down(pz, off);
  }
  int wid = tid >> 6, lane = tid & 63;
  if (lane == 0) { red[wid][0] = px; red[wid][1] = py; red[wid][2] = pz; }
  __syncthreads();
  if (tid < 3) out[row * 3 + tid] = (red[0][tid] + red[1][tid]) * fs[0];
}

extern "C" void kernel_launch(void* const* d_in, const int* in_sizes, int n_in,
                              void* d_out, int out_size, void* d_ws, size_t ws_size,
                              hipStream_t stream) {
  const float* pos  = (const float*)d_in[0];
  const int*   z    = (const int*)d_in[1];
  const float* gf   = (const float*)d_in[2];
  const float* emb  = (const float*)d_in[3];
  const float* Wt   = (const float*)d_in[4];
  const float* Wr1  = (const float*)d_in[5];
  const float* Wr2  = (const float*)d_in[6];
  const float* Wupd = (const float*)d_in[7];
  const float* Wmix = (const float*)d_in[8];
  const float* Wg1  = (const float*)d_in[9];
  const float* Wg2  = (const float*)d_in[10];
  const float* fs   = (const float*)d_in[11];
  float* out = (float*)d_out;

  float* ws = (float*)d_ws;
  const size_t HN = (size_t)BB * NN * HH;   // 524288
  float* hA = ws;
  float* hB = ws + HN;
  float* v  = ws + 2 * HN;                  // 3*HN floats
  unsigned short* Wr2p = (unsigned short*)(ws + 5 * HN);  // 32768 bf16

  dim3 grid(BB * NN);
  k_prep<<<dim3(128), dim3(256), 0, stream>>>(Wr2, Wr2p);
  k_init<<<grid, dim3(128), 0, stream>>>(emb, z, gf, Wt, hA, v);
  k_layer<<<grid, dim3(256), 0, stream>>>(pos, hA, hB, v, Wr1, Wr2p, Wupd, Wmix, 0);
  k_layer<<<grid, dim3(256), 0, stream>>>(pos, hB, hA, v, Wr1, Wr2p, Wupd, Wmix, 1);
  k_readout<<<grid, dim3(128), 0, stream>>>(hA, v, Wg1, Wg2, fs, out);
}

// Round 4
// 191.211 us; speedup vs baseline: 3.5453x; 1.1234x over previous
//
#include <hip/hip_runtime.h>
#include <math.h>

#define NN 64      // nodes per graph
#define HH 128     // hidden channels
#define NBB 8      // bessel basis
#define TT 32      // time embedding dim
#define BB 64      // batch

typedef __attribute__((ext_vector_type(8))) short short8;
typedef __attribute__((ext_vector_type(4))) float f32x4;
typedef __attribute__((ext_vector_type(2))) float f32x2;

__device__ __forceinline__ float silu_f(float x) {
  return x * __builtin_amdgcn_rcpf(1.0f + __expf(-x));
}

__device__ __forceinline__ unsigned short f2bf(float x) {
  union { float f; unsigned u; } v; v.f = x;
  unsigned r = v.u + 0x7FFFu + ((v.u >> 16) & 1u);   // round-to-nearest-even
  return (unsigned short)(r >> 16);
}

// One block per graph b: pack a 512-elem slice of Wr2 -> bf16 B-frag order,
// compute h[b,n,:] = emb[z[b,n],:] + gf[b,:] @ Wt.
__global__ __launch_bounds__(256) void k_init(
    const float* __restrict__ emb, const int* __restrict__ z,
    const float* __restrict__ gf, const float* __restrict__ Wt,
    const float* __restrict__ Wr2, float* __restrict__ h,
    unsigned short* __restrict__ Wr2p) {
  __shared__ float tvec[HH];
  __shared__ int sz[NN];
  int b = blockIdx.x, tid = threadIdx.x;
#pragma unroll
  for (int ii = 0; ii < 2; ++ii) {        // Wr2 pack: dst[(((l*4+kt)*128+n)*4+q)*8+j]
    int idx = b * 512 + ii * 256 + tid;
    int l = idx >> 14, k = (idx >> 7) & 127, n = idx & 127;
    int kt = k >> 5, q = (k >> 3) & 3, j = k & 7;
    Wr2p[((((l * 4 + kt) * 128 + n) * 4 + q) * 8) + j] = f2bf(Wr2[idx]);
  }
  if (tid < NN) sz[tid] = z[b * NN + tid];
  if (tid < HH) {
    float acc = 0.f;
#pragma unroll
    for (int k = 0; k < TT; ++k) acc += gf[b * TT + k] * Wt[k * HH + tid];
    tvec[tid] = acc;
  }
  __syncthreads();
  for (int i = tid; i < NN * HH; i += 256) {
    int n = i >> 7, c = i & 127;
    h[(size_t)b * NN * HH + i] = emb[sz[n] * HH + c] + tvec[c];
  }
}

// One block (256 thr = 4 waves) per (b, receiver r).
// A: rb/u. B: S = silu(rb@Wr1) -> bf16 LDS. GEMM: w = S@Wr2 via mfma.
// Epilogue: m0 = w*h[snd], weight by u, quad-reduce, write a0a1[blk][c][4].
__global__ __launch_bounds__(256) void k_layer(
    const float* __restrict__ pos,
    const float* __restrict__ hin,
    float* __restrict__ a0a1,
    const float* __restrict__ Wr1, const unsigned short* __restrict__ Wr2p,
    int l) {
  __shared__ __align__(16) float sh_pos[NN * 3];
  __shared__ __align__(16) unsigned short sh_S[NN][136];   // +8 pad: conflict-free frags
  __shared__ __align__(16) float sh_rb[NN][8];
  __shared__ __align__(16) float sh_u[NN][4];

  int blk = blockIdx.x;          // b*NN + r
  int b = blk >> 6, r = blk & 63;
  int tid = threadIdx.x;
  int w = tid >> 6, lane = tid & 63;

  if (tid < NN * 3) sh_pos[tid] = pos[b * NN * 3 + tid];
  __syncthreads();

  // ---- Stage A: geometry + bessel basis (threads 0..63, s = tid) ----
  if (tid < NN) {
    int s = tid;
    float dx = sh_pos[r * 3 + 0] - sh_pos[s * 3 + 0];
    float dy = sh_pos[r * 3 + 1] - sh_pos[s * 3 + 1];
    float dz = sh_pos[r * 3 + 2] - sh_pos[s * 3 + 2];
    float rr = sqrtf(dx * dx + dy * dy + dz * dz + 1e-12f);
    float inv = __builtin_amdgcn_rcpf(rr);
    sh_u[s][0] = dx * inv; sh_u[s][1] = dy * inv; sh_u[s][2] = dz * inv; sh_u[s][3] = 0.f;
    const float PI_OVER_5 = 0.628318530717958647692f;
    float fc = (s != r && rr < 5.0f) ? 0.5f * (__cosf(PI_OVER_5 * rr) + 1.0f) : 0.0f;
    float base = PI_OVER_5 * rr;
    float sc = inv * fc;
#pragma unroll
    for (int k = 0; k < NBB; ++k)
      sh_rb[s][k] = __sinf((float)(k + 1) * base) * sc;
  }
  __syncthreads();

  // ---- Stage B: S[s][c] = silu(rb[s]@Wr1[:,c]) -> bf16; wave w: s in [w*16, w*16+16) ----
  {
    const float* Wr1l = Wr1 + l * NBB * HH;
    int c0 = 2 * lane;
    float wc0[NBB], wc1[NBB];
#pragma unroll
    for (int k = 0; k < NBB; ++k) { wc0[k] = Wr1l[k * HH + c0]; wc1[k] = Wr1l[k * HH + c0 + 1]; }
    int sbase = w * 16;
#pragma unroll 4
    for (int si = 0; si < 16; ++si) {
      int s = sbase + si;
      f32x4 r0 = *(const f32x4*)&sh_rb[s][0];
      f32x4 r1 = *(const f32x4*)&sh_rb[s][4];
      float a0 = r0.x*wc0[0] + r0.y*wc0[1] + r0.z*wc0[2] + r0.w*wc0[3]
               + r1.x*wc0[4] + r1.y*wc0[5] + r1.z*wc0[6] + r1.w*wc0[7];
      float a1 = r0.x*wc1[0] + r0.y*wc1[1] + r0.z*wc1[2] + r0.w*wc1[3]
               + r1.x*wc1[4] + r1.y*wc1[5] + r1.z*wc1[6] + r1.w*wc1[7];
      unsigned packed = (unsigned)f2bf(silu_f(a0)) | ((unsigned)f2bf(silu_f(a1)) << 16);
      *(unsigned*)&sh_S[s][c0] = packed;
    }
  }
  __syncthreads();

  // ---- GEMM + message epilogue (wave w owns c in [w*32, w*32+32)) ----
  const unsigned short* Bbase = Wr2p + l * 16384;
  int nlo = lane & 15, quad = lane >> 4;
  short8 bfr[4][2];
#pragma unroll
  for (int kt = 0; kt < 4; ++kt)
#pragma unroll
    for (int nt = 0; nt < 2; ++nt) {
      int c = w * 32 + nt * 16 + nlo;
      bfr[kt][nt] = *(const short8*)&Bbase[((kt * 128 + c) * 4 + quad) * 8];
    }
  float acc0[2] = {0.f, 0.f};
  float a1x[2] = {0.f, 0.f};
  float a1y[2] = {0.f, 0.f};
  float a1z[2] = {0.f, 0.f};
  const float* hb = hin + (size_t)b * NN * HH;

#pragma unroll
  for (int mt = 0; mt < 4; ++mt) {
    short8 afr[4];
    int s_a = mt * 16 + nlo;
#pragma unroll
    for (int kt = 0; kt < 4; ++kt)
      afr[kt] = *(const short8*)&sh_S[s_a][kt * 32 + quad * 8];
    float ux[4], uy[4], uz[4];
#pragma unroll
    for (int reg = 0; reg < 4; ++reg) {
      int s = mt * 16 + quad * 4 + reg;
      ux[reg] = sh_u[s][0]; uy[reg] = sh_u[s][1]; uz[reg] = sh_u[s][2];
    }
#pragma unroll
    for (int nt = 0; nt < 2; ++nt) {
      int c = w * 32 + nt * 16 + nlo;
      f32x4 C = {0.f, 0.f, 0.f, 0.f};
#pragma unroll
      for (int kt = 0; kt < 4; ++kt)
        C = __builtin_amdgcn_mfma_f32_16x16x32_bf16(afr[kt], bfr[kt][nt], C, 0, 0, 0);
#pragma unroll
      for (int reg = 0; reg < 4; ++reg) {
        int s = mt * 16 + quad * 4 + reg;
        float m0 = C[reg] * hb[s * HH + c];
        acc0[nt] += m0;
        a1x[nt] += m0 * ux[reg];
        a1y[nt] += m0 * uy[reg];
        a1z[nt] += m0 * uz[reg];
      }
    }
  }

  // quad-reduce -> global a0a1[blk][c][{a0,a1x,a1y,a1z}]
  const float invAvg = 1.0f / 63.0f;
#pragma unroll
  for (int nt = 0; nt < 2; ++nt) {
    float q0 = acc0[nt], q1 = a1x[nt], q2 = a1y[nt], q3 = a1z[nt];
    q0 += __shfl_xor(q0, 16); q0 += __shfl_xor(q0, 32);
    q1 += __shfl_xor(q1, 16); q1 += __shfl_xor(q1, 32);
    q2 += __shfl_xor(q2, 16); q2 += __shfl_xor(q2, 32);
    q3 += __shfl_xor(q3, 16); q3 += __shfl_xor(q3, 32);
    if (quad == 0) {
      int c = w * 32 + nt * 16 + nlo;
      f32x4 val = {q0 * invAvg, q1 * invAvg, q2 * invAvg, q3 * invAvg};
      *(f32x4*)&a0a1[((size_t)blk * HH + c) * 4] = val;
    }
  }
}

// Batched node update, 8 rows/block: hout = hin + a0@Wul ; v = a1@Wml (write).
__global__ __launch_bounds__(256) void k_update(
    const float* __restrict__ a0a1, const float* __restrict__ hin,
    float* __restrict__ hout, float* __restrict__ v,
    const float* __restrict__ Wul, const float* __restrict__ Wml) {
  __shared__ __align__(16) f32x4 sh_a[8][HH];
  int tid = threadIdx.x;
  int row0 = blockIdx.x * 8;
  const f32x4* src = (const f32x4*)(a0a1 + (size_t)row0 * HH * 4);
  for (int i = tid; i < 8 * HH; i += 256) sh_a[i >> 7][i & 127] = src[i];
  __syncthreads();
  int cp = (tid & 63) * 2;
  int rg = tid >> 6;                     // rows rg*2, rg*2+1
  float h00=0,h01=0,h10=0,h11=0;
  float x00=0,x01=0,x10=0,x11=0;
  float y00=0,y01=0,y10=0,y11=0;
  float z00=0,z01=0,z10=0,z11=0;
#pragma unroll 4
  for (int g = 0; g < HH; ++g) {
    f32x2 wu = *(const f32x2*)&Wul[g * HH + cp];
    f32x2 wm = *(const f32x2*)&Wml[g * HH + cp];
    f32x4 aA = sh_a[rg * 2][g];
    f32x4 aB = sh_a[rg * 2 + 1][g];
    h00 += aA.x*wu.x; h01 += aA.x*wu.y; h10 += aB.x*wu.x; h11 += aB.x*wu.y;
    x00 += aA.y*wm.x; x01 += aA.y*wm.y; x10 += aB.y*wm.x; x11 += aB.y*wm.y;
    y00 += aA.z*wm.x; y01 += aA.z*wm.y; y10 += aB.z*wm.x; y11 += aB.z*wm.y;
    z00 += aA.w*wm.x; z01 += aA.w*wm.y; z10 += aB.w*wm.x; z11 += aB.w*wm.y;
  }
  size_t rA = row0 + rg * 2, rB = rA + 1;
  f32x2 hA2 = *(const f32x2*)&hin[rA * HH + cp];
  f32x2 hB2 = *(const f32x2*)&hin[rB * HH + cp];
  f32x2 t;
  t.x = hA2.x + h00; t.y = hA2.y + h01; *(f32x2*)&hout[rA * HH + cp] = t;
  t.x = hB2.x + h10; t.y = hB2.y + h11; *(f32x2*)&hout[rB * HH + cp] = t;
  t.x = x00; t.y = x01; *(f32x2*)&v[(rA * 3 + 0) * HH + cp] = t;
  t.x = y00; t.y = y01; *(f32x2*)&v[(rA * 3 + 1) * HH + cp] = t;
  t.x = z00; t.y = z01; *(f32x2*)&v[(rA * 3 + 2) * HH + cp] = t;
  t.x = x10; t.y = x11; *(f32x2*)&v[(rB * 3 + 0) * HH + cp] = t;
  t.x = y10; t.y = y11; *(f32x2*)&v[(rB * 3 + 1) * HH + cp] = t;
  t.x = z10; t.y = z11; *(f32x2*)&v[(rB * 3 + 2) * HH + cp] = t;
}

// Layer-1 update fused with readout: h/v rows stay in LDS; g = silu(h@Wg1)@Wg2;
// out[n,d] = sum_c v[n,c,d]*g[n,c] * fs.
__global__ __launch_bounds__(256) void k_update_ro(
    const float* __restrict__ a0a1, const float* __restrict__ hin,
    const float* __restrict__ v,
    const float* __restrict__ Wul, const float* __restrict__ Wml,
    const float* __restrict__ Wg1, const float* __restrict__ Wg2,
    const float* __restrict__ fs, float* __restrict__ out) {
  __shared__ __align__(16) f32x4 sh_a[8][HH];    // 16 KB
  __shared__ float sh_h[8][HH];                  // 4 KB
  __shared__ float sh_v[8][3][HH];               // 12 KB
  __shared__ float sh_q[8][HH];                  // 4 KB
  __shared__ float sh_g[8][HH];                  // 4 KB
  int tid = threadIdx.x;
  int row0 = blockIdx.x * 8;
  const f32x4* src = (const f32x4*)(a0a1 + (size_t)row0 * HH * 4);
  for (int i = tid; i < 8 * HH; i += 256) sh_a[i >> 7][i & 127] = src[i];
  __syncthreads();
  {
    int cp = (tid & 63) * 2;
    int rg = tid >> 6;
    float h00=0,h01=0,h10=0,h11=0;
    float x00=0,x01=0,x10=0,x11=0;
    float y00=0,y01=0,y10=0,y11=0;
    float z00=0,z01=0,z10=0,z11=0;
#pragma unroll 4
    for (int g = 0; g < HH; ++g) {
      f32x2 wu = *(const f32x2*)&Wul[g * HH + cp];
      f32x2 wm = *(const f32x2*)&Wml[g * HH + cp];
      f32x4 aA = sh_a[rg * 2][g];
      f32x4 aB = sh_a[rg * 2 + 1][g];
      h00 += aA.x*wu.x; h01 += aA.x*wu.y; h10 += aB.x*wu.x; h11 += aB.x*wu.y;
      x00 += aA.y*wm.x; x01 += aA.y*wm.y; x10 += aB.y*wm.x; x11 += aB.y*wm.y;
      y00 += aA.z*wm.x; y01 += aA.z*wm.y; y10 += aB.z*wm.x; y11 += aB.z*wm.y;
      z00 += aA.w*wm.x; z01 += aA.w*wm.y; z10 += aB.w*wm.x; z11 += aB.w*wm.y;
    }
    size_t rA = row0 + rg * 2, rB = rA + 1;
    int lrA = rg * 2, lrB = lrA + 1;
    sh_h[lrA][cp]     = hin[rA * HH + cp]     + h00;
    sh_h[lrA][cp + 1] = hin[rA * HH + cp + 1] + h01;
    sh_h[lrB][cp]     = hin[rB * HH + cp]     + h10;
    sh_h[lrB][cp + 1] = hin[rB * HH + cp + 1] + h11;
    sh_v[lrA][0][cp]     = v[(rA * 3 + 0) * HH + cp]     + x00;
    sh_v[lrA][0][cp + 1] = v[(rA * 3 + 0) * HH + cp + 1] + x01;
    sh_v[lrA][1][cp]     = v[(rA * 3 + 1) * HH + cp]     + y00;
    sh_v[lrA][1][cp + 1] = v[(rA * 3 + 1) * HH + cp + 1] + y01;
    sh_v[lrA][2][cp]     = v[(rA * 3 + 2) * HH + cp]     + z00;
    sh_v[lrA][2][cp + 1] = v[(rA * 3 + 2) * HH + cp + 1] + z01;
    sh_v[lrB][0][cp]     = v[(rB * 3 + 0) * HH + cp]     + x10;
    sh_v[lrB][0][cp + 1] = v[(rB * 3 + 0) * HH + cp + 1] + x11;
    sh_v[lrB][1][cp]     = v[(rB * 3 + 1) * HH + cp]     + y10;
    sh_v[lrB][1][cp + 1] = v[(rB * 3 + 1) * HH + cp + 1] + y11;
    sh_v[lrB][2][cp]     = v[(rB * 3 + 2) * HH + cp]     + z10;
    sh_v[lrB][2][cp + 1] = v[(rB * 3 + 2) * HH + cp + 1] + z11;
  }
  __syncthreads();
  // gate GEMM 1: q = silu(h @ Wg1)
  {
    int c = tid & 127, r4 = (tid >> 7) * 4;
    float q[4] = {0.f, 0.f, 0.f, 0.f};
    for (int k = 0; k < HH; ++k) {
      float wg = Wg1[k * HH + c];
#pragma unroll
      for (int j = 0; j < 4; ++j) q[j] += sh_h[r4 + j][k] * wg;
    }
#pragma unroll
    for (int j = 0; j < 4; ++j) sh_q[r4 + j][c] = silu_f(q[j]);
  }
  __syncthreads();
  // gate GEMM 2: g = q @ Wg2
  {
    int c = tid & 127, r4 = (tid >> 7) * 4;
    float gg[4] = {0.f, 0.f, 0.f, 0.f};
    for (int k = 0; k < HH; ++k) {
      float wg = Wg2[k * HH + c];
#pragma unroll
      for (int j = 0; j < 4; ++j) gg[j] += sh_q[r4 + j][k] * wg;
    }
#pragma unroll
    for (int j = 0; j < 4; ++j) sh_g[r4 + j][c] = gg[j];
  }
  __syncthreads();
  // contraction: out[row,d] = sum_c v[row][d][c]*g[row][c]
  {
    int row = tid >> 5, i = tid & 31;
    float px = 0.f, py = 0.f, pz = 0.f;
    for (int cc = i; cc < HH; cc += 32) {
      float gv = sh_g[row][cc];
      px += sh_v[row][0][cc] * gv;
      py += sh_v[row][1][cc] * gv;
      pz += sh_v[row][2][cc] * gv;
    }
#pragma unroll
    for (int off = 16; off > 0; off >>= 1) {
      px += __shfl_down(px, off);
      py += __shfl_down(py, off);
      pz += __shfl_down(pz, off);
    }
    if (i == 0) {
      float s = fs[0];
      size_t o = ((size_t)(row0 + row)) * 3;
      out[o + 0] = px * s; out[o + 1] = py * s; out[o + 2] = pz * s;
    }
  }
}

extern "C" void kernel_launch(void* const* d_in, const int* in_sizes, int n_in,
                              void* d_out, int out_size, void* d_ws, size_t ws_size,
                              hipStream_t stream) {
  const float* pos  = (const float*)d_in[0];
  const int*   z    = (const int*)d_in[1];
  const float* gf   = (const float*)d_in[2];
  const float* emb  = (const float*)d_in[3];
  const float* Wt   = (const float*)d_in[4];
  const float* Wr1  = (const float*)d_in[5];
  const float* Wr2  = (const float*)d_in[6];
  const float* Wupd = (const float*)d_in[7];
  const float* Wmix = (const float*)d_in[8];
  const float* Wg1  = (const float*)d_in[9];
  const float* Wg2  = (const float*)d_in[10];
  const float* fs   = (const float*)d_in[11];
  float* out = (float*)d_out;

  float* ws = (float*)d_ws;
  const size_t HN = (size_t)BB * NN * HH;   // 524288
  float* hA   = ws;                          // 2 MB
  float* hB   = ws + HN;                     // 2 MB
  float* v    = ws + 2 * HN;                 // 6 MB
  float* a0a1 = ws + 5 * HN;                 // 8 MB ([4096][128][4])
  unsigned short* Wr2p = (unsigned short*)(ws + 9 * HN);  // 64 KB

  k_init<<<dim3(BB), dim3(256), 0, stream>>>(emb, z, gf, Wt, Wr2, hA, Wr2p);
  k_layer<<<dim3(BB * NN), dim3(256), 0, stream>>>(pos, hA, a0a1, Wr1, Wr2p, 0);
  k_update<<<dim3(512), dim3(256), 0, stream>>>(a0a1, hA, hB, v, Wupd, Wmix);
  k_layer<<<dim3(BB * NN), dim3(256), 0, stream>>>(pos, hB, a0a1, Wr1, Wr2p, 1);
  k_update_ro<<<dim3(512), dim3(256), 0, stream>>>(a0a1, hB, v,
      Wupd + 16384, Wmix + 16384, Wg1, Wg2, fs, out);
}